// Round 1
// baseline (199.668 us; speedup 1.0000x reference)
//
#include <hip/hip_runtime.h>

// MultiHeadAttention: x@Wq/Wk/Wv -> causal flash attn -> @Wo
// B=2 S=2048 H=16 D=64 HIDDEN=1024. All MFMA in bf16 (16x16x32), f32 accum.
//
// Workspace map (needs 64 MiB):
//   [0)         xq,xk,xv bf16      3 * 8 MiB
//   [25165824)  wqT,wkT,wvT,woT    4 * 2 MiB   (bf16, transposed to [N][K])
//   [33554432)  Qb  bf16 [4096][1024]
//   [41943040)  Kb  bf16 [4096][1024]
//   [50331648)  VTb bf16 [b][h][d][s] = [2][16][64][2048]
//   [58720256)  Ob  bf16 [4096][1024]  (attn output, pre-projection)

using u16 = unsigned short;
typedef __bf16 bf16x8 __attribute__((ext_vector_type(8)));
typedef short  s16x8  __attribute__((ext_vector_type(8)));
typedef float  f32x4  __attribute__((ext_vector_type(4)));
typedef unsigned short u16x4 __attribute__((ext_vector_type(4)));

#define SEQ   2048
#define NHEAD 16
#define SCALE 0.125f

__device__ __forceinline__ u16 to_bf16(float f) {
  return __builtin_bit_cast(u16, (__bf16)f);
}
__device__ __forceinline__ bf16x8 frag_cast(s16x8 v) {
  return __builtin_bit_cast(bf16x8, v);
}
__device__ __forceinline__ f32x4 mfma16(bf16x8 a, bf16x8 b, f32x4 c) {
  return __builtin_amdgcn_mfma_f32_16x16x32_bf16(a, b, c, 0, 0, 0);
}
__device__ __forceinline__ void gload_lds16(const void* g, void* l) {
  __builtin_amdgcn_global_load_lds(
      (const __attribute__((address_space(1))) void*)g,
      (__attribute__((address_space(3))) void*)l, 16, 0, 0);
}

// ---------------- f32 -> bf16 convert (query/key/value) -------------------
__global__ __launch_bounds__(256) void convert_x(const float* __restrict__ q,
                                                 const float* __restrict__ k,
                                                 const float* __restrict__ v,
                                                 u16* __restrict__ out) {
  const float* src = blockIdx.z == 0 ? q : (blockIdx.z == 1 ? k : v);
  u16* dst = out + (size_t)blockIdx.z * 4194304;
  for (int idx = blockIdx.x * 256 + threadIdx.x; idx < 524288; idx += 512 * 256) {
    const float4* p = (const float4*)(src + (size_t)idx * 8);
    float4 a = p[0], b = p[1];
    s16x8 o;
    o[0] = (short)to_bf16(a.x); o[1] = (short)to_bf16(a.y);
    o[2] = (short)to_bf16(a.z); o[3] = (short)to_bf16(a.w);
    o[4] = (short)to_bf16(b.x); o[5] = (short)to_bf16(b.y);
    o[6] = (short)to_bf16(b.z); o[7] = (short)to_bf16(b.w);
    *(s16x8*)(dst + (size_t)idx * 8) = o;
  }
}

// ---------------- weight transpose+convert: w[K][N] f32 -> wT[N][K] bf16 --
__global__ __launch_bounds__(256) void transpose_w(const float* __restrict__ wq,
                                                   const float* __restrict__ wk,
                                                   const float* __restrict__ wv,
                                                   const float* __restrict__ wo,
                                                   u16* __restrict__ wT) {
  __shared__ float tile[32][33];
  const float* src = blockIdx.z == 0 ? wq : blockIdx.z == 1 ? wk
                     : blockIdx.z == 2 ? wv : wo;
  u16* dst = wT + (size_t)blockIdx.z * 1048576;
  const int x0 = blockIdx.x * 32, y0 = blockIdx.y * 32;
  const int tx = threadIdx.x, ty = threadIdx.y;  // block (32,8)
#pragma unroll
  for (int i = 0; i < 4; ++i)
    tile[ty + i * 8][tx] = src[(size_t)(y0 + ty + i * 8) * 1024 + x0 + tx];
  __syncthreads();
#pragma unroll
  for (int i = 0; i < 4; ++i)
    dst[(size_t)(x0 + ty + i * 8) * 1024 + y0 + tx] = to_bf16(tile[tx][ty + i * 8]);
}

// ---------------- 128x128 bf16 GEMM, A[M][K] * BT[N][K]^T -----------------
// OUT=0: bf16 C[row*1024+col]; OUT=1: bf16 V^T layout [b][h][d][s]; OUT=2: f32
template <int OUT>
__global__ __launch_bounds__(256) void gemm_bt(const u16* __restrict__ A,
                                               const u16* __restrict__ BT,
                                               void* __restrict__ Cv) {
  __shared__ u16 As[128 * 32];
  __shared__ u16 Bs[128 * 32];
  const int tid = threadIdx.x;
  const int w = tid >> 6, lane = tid & 63;
  const int g = lane >> 4, c = lane & 15;
  const int wr = w >> 1, wc = w & 1;
  const int row0 = blockIdx.x * 128;
  const int n0 = blockIdx.y * 128;

  f32x4 acc[4][4];
#pragma unroll
  for (int i = 0; i < 4; ++i)
#pragma unroll
    for (int j = 0; j < 4; ++j) acc[i][j] = (f32x4){0.f, 0.f, 0.f, 0.f};

  const int sub = lane >> 2;       // row within 16-row chunk
  const int kk = (lane & 3) * 8;   // k element offset

  for (int kt = 0; kt < 32; ++kt) {
    const int k0 = kt * 32;
#pragma unroll
    for (int it = 0; it < 2; ++it) {
      const int ch = w * 2 + it;  // 0..7, wave-uniform
      const int row = ch * 16 + sub;
      gload_lds16(A + (size_t)(row0 + row) * 1024 + k0 + kk, (char*)As + ch * 1024);
      gload_lds16(BT + (size_t)(n0 + row) * 1024 + k0 + kk, (char*)Bs + ch * 1024);
    }
    __syncthreads();

    bf16x8 af[4], bfr[4];
#pragma unroll
    for (int mi = 0; mi < 4; ++mi) {
      const int r = wr * 64 + mi * 16 + c;
      af[mi] = frag_cast(*(const s16x8*)((const char*)As + r * 64 + g * 16));
    }
#pragma unroll
    for (int ni = 0; ni < 4; ++ni) {
      const int r = wc * 64 + ni * 16 + c;
      bfr[ni] = frag_cast(*(const s16x8*)((const char*)Bs + r * 64 + g * 16));
    }
#pragma unroll
    for (int mi = 0; mi < 4; ++mi)
#pragma unroll
      for (int ni = 0; ni < 4; ++ni)
        acc[mi][ni] = mfma16(af[mi], bfr[ni], acc[mi][ni]);
    __syncthreads();
  }

#pragma unroll
  for (int mi = 0; mi < 4; ++mi) {
    const int rowb = row0 + wr * 64 + mi * 16 + g * 4;
#pragma unroll
    for (int ni = 0; ni < 4; ++ni) {
      const int col = n0 + wc * 64 + ni * 16 + c;
#pragma unroll
      for (int r = 0; r < 4; ++r) {
        const int row = rowb + r;
        const float v = acc[mi][ni][r];
        if constexpr (OUT == 0) {
          ((u16*)Cv)[(size_t)row * 1024 + col] = to_bf16(v);
        } else if constexpr (OUT == 1) {
          const int b = row >> 11, s = row & 2047;
          const int hh = col >> 6, d = col & 63;
          ((u16*)Cv)[((size_t)((b * 16 + hh) * 64 + d)) * 2048 + s] = to_bf16(v);
        } else {
          ((float*)Cv)[(size_t)row * 1024 + col] = v;
        }
      }
    }
  }
}

// ---------------- causal flash attention ----------------------------------
// grid (16, 32): x = q-tile (128 rows), y = b*16+h. 4 waves x 32 q-rows.
// Swapped QK^T: S^T[kv][q] = mfma(A=K, B=Q). Online softmax per q-column.
__global__ __launch_bounds__(256) void attn_fwd(const u16* __restrict__ Qb,
                                                const u16* __restrict__ Kb,
                                                const u16* __restrict__ VTb,
                                                u16* __restrict__ Ob) {
  __shared__ u16 Ks[64 * 64];        // [kv][d] swizzled
  __shared__ u16 VTs[64 * 64];       // [d][kv] swizzled
  __shared__ u16 Ps[4][32 * 64];     // per-wave [q][kv] swizzled

  const int tid = threadIdx.x;
  const int w = tid >> 6, lane = tid & 63;
  const int g = lane >> 4, c = lane & 15;
  const int qt = blockIdx.x;
  const int bh = blockIdx.y;
  const int b = bh >> 4, h = bh & 15;
  const int q0w = qt * 128 + w * 32;

  // Q fragments live in registers the whole kernel (B-operand: n=q, k=d)
  bf16x8 qfr[2][2];
#pragma unroll
  for (int qf = 0; qf < 2; ++qf)
#pragma unroll
    for (int ch = 0; ch < 2; ++ch) {
      const int q = q0w + qf * 16 + c;
      const int d = ch * 32 + g * 8;
      qfr[qf][ch] = frag_cast(*(const s16x8*)(Qb + (size_t)(b * SEQ + q) * 1024 + h * 64 + d));
    }

  f32x4 oacc[2][4];
#pragma unroll
  for (int i = 0; i < 2; ++i)
#pragma unroll
    for (int j = 0; j < 4; ++j) oacc[i][j] = (f32x4){0.f, 0.f, 0.f, 0.f};
  float m_run[2] = {-1e30f, -1e30f};
  float l_run[2] = {0.f, 0.f};

  const int T = 2 * (qt + 1);        // causal: kv tiles 0..T-1
  const int srow = tid >> 3;         // 0..31
  const int scol = (tid & 7) * 8;    // 0..56

  for (int t = 0; t < T; ++t) {
    const int kv0 = t * 64;
    // stage K tile [64][64] and V^T tile [64][64], XOR-swizzled rows
#pragma unroll
    for (int it = 0; it < 2; ++it) {
      const int r = srow + it * 32;
      const s16x8 kvv = *(const s16x8*)(Kb + (size_t)(b * SEQ + kv0 + r) * 1024 + h * 64 + scol);
      const s16x8 vvv = *(const s16x8*)(VTb + ((size_t)(bh * 64 + r)) * 2048 + kv0 + scol);
      const int sw = (scol * 2) ^ ((r & 7) << 4);
      *(s16x8*)((char*)Ks + r * 128 + sw) = kvv;
      *(s16x8*)((char*)VTs + r * 128 + sw) = vvv;
    }
    __syncthreads();

    if (kv0 <= q0w + 31) {           // wave has at least one unmasked row
      // ---- S^T = K * Q^T : [kv 64][q 32] = 4 kvf x 2 qf frags
      f32x4 sa[4][2];
#pragma unroll
      for (int i = 0; i < 4; ++i)
#pragma unroll
        for (int j = 0; j < 2; ++j) sa[i][j] = (f32x4){0.f, 0.f, 0.f, 0.f};
#pragma unroll
      for (int kvf = 0; kvf < 4; ++kvf) {
        const int kr = kvf * 16 + c;
        const int rb = kr * 128, swz = (kr & 7) << 4;
#pragma unroll
        for (int ch = 0; ch < 2; ++ch) {
          const bf16x8 ak = frag_cast(*(const s16x8*)((char*)Ks + rb + ((ch * 64 + g * 16) ^ swz)));
#pragma unroll
          for (int qf = 0; qf < 2; ++qf)
            sa[kvf][qf] = mfma16(ak, qfr[qf][ch], sa[kvf][qf]);
        }
      }
      // ---- scale + causal mask + online softmax (per q-column = lane c)
#pragma unroll
      for (int qf = 0; qf < 2; ++qf) {
        const int q_abs = q0w + qf * 16 + c;
        float pv[4][4];
        float mt = -1e30f;
#pragma unroll
        for (int kvf = 0; kvf < 4; ++kvf)
#pragma unroll
          for (int r = 0; r < 4; ++r) {
            const int kv_abs = kv0 + kvf * 16 + g * 4 + r;
            float s = sa[kvf][qf][r] * SCALE;
            if (kv_abs > q_abs) s -= 10000.f;   // matches ref additive mask
            pv[kvf][r] = s;
            mt = fmaxf(mt, s);
          }
        mt = fmaxf(mt, __shfl_xor(mt, 16));
        mt = fmaxf(mt, __shfl_xor(mt, 32));
        const float m_new = fmaxf(m_run[qf], mt);
        const float alpha = __expf(m_run[qf] - m_new);
        m_run[qf] = m_new;
        float ls = 0.f;
        const int qrow = qf * 16 + c;
        const int qswz = (qrow & 7) << 4;
#pragma unroll
        for (int kvf = 0; kvf < 4; ++kvf) {
          u16x4 pk;
#pragma unroll
          for (int r = 0; r < 4; ++r) {
            const float p = __expf(pv[kvf][r] - m_new);
            ls += p;
            pk[r] = to_bf16(p);
          }
          *(u16x4*)((char*)Ps[w] + qrow * 128 + (((kvf * 16 + g * 4) * 2) ^ qswz)) = pk;
        }
        ls += __shfl_xor(ls, 16);
        ls += __shfl_xor(ls, 32);
        l_run[qf] = l_run[qf] * alpha + ls;
        // rescale O accumulator: rows q = 4g+r need alpha from column-lane 4g+r
#pragma unroll
        for (int r = 0; r < 4; ++r) {
          const float ar = __shfl(alpha, g * 4 + r);
#pragma unroll
          for (int df = 0; df < 4; ++df) oacc[qf][df][r] *= ar;
        }
      }
      // ---- O += P * V  (A = P from LDS, B = V^T tile)
#pragma unroll
      for (int ch = 0; ch < 2; ++ch) {
        bf16x8 ap[2];
#pragma unroll
        for (int qf = 0; qf < 2; ++qf) {
          const int qrow = qf * 16 + c;
          ap[qf] = frag_cast(*(const s16x8*)((char*)Ps[w] + qrow * 128 +
                                             ((ch * 64 + g * 16) ^ ((qrow & 7) << 4))));
        }
#pragma unroll
        for (int df = 0; df < 4; ++df) {
          const int dr = df * 16 + c;
          const bf16x8 bv = frag_cast(*(const s16x8*)((char*)VTs + dr * 128 +
                                                      ((ch * 64 + g * 16) ^ ((dr & 7) << 4))));
#pragma unroll
          for (int qf = 0; qf < 2; ++qf)
            oacc[qf][df] = mfma16(ap[qf], bv, oacc[qf][df]);
        }
      }
    }
    __syncthreads();
  }

  // epilogue: normalize by l_run and store bf16 [b][s][h*64+d]
#pragma unroll
  for (int qf = 0; qf < 2; ++qf) {
    const float li = 1.f / l_run[qf];
#pragma unroll
    for (int r = 0; r < 4; ++r) {
      const float lr = __shfl(li, g * 4 + r);
      const int q_abs = q0w + qf * 16 + g * 4 + r;
#pragma unroll
      for (int df = 0; df < 4; ++df) {
        const int col = h * 64 + df * 16 + c;
        Ob[(size_t)(b * SEQ + q_abs) * 1024 + col] = to_bf16(oacc[qf][df][r] * lr);
      }
    }
  }
}

// --------------------------------------------------------------------------
extern "C" void kernel_launch(void* const* d_in, const int* in_sizes, int n_in,
                              void* d_out, int out_size, void* d_ws, size_t ws_size,
                              hipStream_t stream) {
  const float* query = (const float*)d_in[0];
  const float* key_ = (const float*)d_in[1];
  const float* value = (const float*)d_in[2];
  const float* w_q = (const float*)d_in[3];
  const float* w_k = (const float*)d_in[4];
  const float* w_v = (const float*)d_in[5];
  const float* w_o = (const float*)d_in[6];

  char* ws = (char*)d_ws;
  u16* xq = (u16*)(ws + 0);
  u16* xk = xq + 4194304;
  u16* xv = xk + 4194304;
  u16* wT = (u16*)(ws + 25165824);
  u16* Qb = (u16*)(ws + 33554432);
  u16* Kb = (u16*)(ws + 41943040);
  u16* VTb = (u16*)(ws + 50331648);
  u16* Ob = (u16*)(ws + 58720256);

  convert_x<<<dim3(512, 1, 3), 256, 0, stream>>>(query, key_, value, xq);
  transpose_w<<<dim3(32, 32, 4), dim3(32, 8), 0, stream>>>(w_q, w_k, w_v, w_o, wT);
  gemm_bt<0><<<dim3(32, 8), 256, 0, stream>>>(xq, wT, Qb);
  gemm_bt<0><<<dim3(32, 8), 256, 0, stream>>>(xk, wT + 1048576, Kb);
  gemm_bt<1><<<dim3(32, 8), 256, 0, stream>>>(xv, wT + 2097152, VTb);
  attn_fwd<<<dim3(16, 32), 256, 0, stream>>>(Qb, Kb, VTb, Ob);
  gemm_bt<2><<<dim3(32, 8), 256, 0, stream>>>(Ob, wT + 3145728, (float*)d_out);
}

// Round 2
// 140.263 us; speedup vs baseline: 1.4235x; 1.4235x over previous
//
#include <hip/hip_runtime.h>

// MultiHeadAttention: x@Wq/Wk/Wv -> causal flash attn -> @Wo
// B=2 S=2048 H=16 D=64 HIDDEN=1024. All MFMA bf16 16x16x32, f32 accum.
//
// R1 changes vs R0:
//  - attn: 64 q-rows/block (4 waves x 16), grid (32,32)=1024 blocks; uniform
//    causal split (t<qt live, t==qt diagonal); exp2-domain softmax (Q
//    pre-scaled by SCALE*log2e in GEMM epilogue); defer-max (THR=8).
//  - QKV GEMMs fused into one dispatch (blockIdx.z), 768 blocks.
//  - out-proj GEMM BM=64 -> 512 blocks.
//
// Workspace map (64 MiB):
//   [0)         xq,xk,xv bf16      3 * 8 MiB   (contiguous: z*4194304)
//   [25165824)  wqT,wkT,wvT,woT    4 * 2 MiB   (bf16, [N][K])
//   [33554432)  Qb  bf16 [4096][1024]  (pre-scaled by 0.125*log2e)
//   [41943040)  Kb  bf16 [4096][1024]
//   [50331648)  VTb bf16 [b][h][d][s] = [2][16][64][2048]
//   [58720256)  Ob  bf16 [4096][1024]

using u16 = unsigned short;
typedef __bf16 bf16x8 __attribute__((ext_vector_type(8)));
typedef short  s16x8  __attribute__((ext_vector_type(8)));
typedef float  f32x4  __attribute__((ext_vector_type(4)));
typedef unsigned short u16x4 __attribute__((ext_vector_type(4)));

#define SEQ   2048
#define QSC   0.18033688f   /* 0.125 * log2(e) */

__device__ __forceinline__ u16 to_bf16(float f) {
  return __builtin_bit_cast(u16, (__bf16)f);
}
__device__ __forceinline__ bf16x8 frag_cast(s16x8 v) {
  return __builtin_bit_cast(bf16x8, v);
}
__device__ __forceinline__ f32x4 mfma16(bf16x8 a, bf16x8 b, f32x4 c) {
  return __builtin_amdgcn_mfma_f32_16x16x32_bf16(a, b, c, 0, 0, 0);
}
__device__ __forceinline__ void gload_lds16(const void* g, void* l) {
  __builtin_amdgcn_global_load_lds(
      (const __attribute__((address_space(1))) void*)g,
      (__attribute__((address_space(3))) void*)l, 16, 0, 0);
}

// ---------------- f32 -> bf16 convert (query/key/value) -------------------
__global__ __launch_bounds__(256) void convert_x(const float* __restrict__ q,
                                                 const float* __restrict__ k,
                                                 const float* __restrict__ v,
                                                 u16* __restrict__ out) {
  const float* src = blockIdx.z == 0 ? q : (blockIdx.z == 1 ? k : v);
  u16* dst = out + (size_t)blockIdx.z * 4194304;
  for (int idx = blockIdx.x * 256 + threadIdx.x; idx < 524288; idx += 512 * 256) {
    const float4* p = (const float4*)(src + (size_t)idx * 8);
    float4 a = p[0], b = p[1];
    s16x8 o;
    o[0] = (short)to_bf16(a.x); o[1] = (short)to_bf16(a.y);
    o[2] = (short)to_bf16(a.z); o[3] = (short)to_bf16(a.w);
    o[4] = (short)to_bf16(b.x); o[5] = (short)to_bf16(b.y);
    o[6] = (short)to_bf16(b.z); o[7] = (short)to_bf16(b.w);
    *(s16x8*)(dst + (size_t)idx * 8) = o;
  }
}

// ---------------- weight transpose+convert: w[K][N] f32 -> wT[N][K] bf16 --
__global__ __launch_bounds__(256) void transpose_w(const float* __restrict__ wq,
                                                   const float* __restrict__ wk,
                                                   const float* __restrict__ wv,
                                                   const float* __restrict__ wo,
                                                   u16* __restrict__ wT) {
  __shared__ float tile[32][33];
  const float* src = blockIdx.z == 0 ? wq : blockIdx.z == 1 ? wk
                     : blockIdx.z == 2 ? wv : wo;
  u16* dst = wT + (size_t)blockIdx.z * 1048576;
  const int x0 = blockIdx.x * 32, y0 = blockIdx.y * 32;
  const int tx = threadIdx.x, ty = threadIdx.y;  // block (32,8)
#pragma unroll
  for (int i = 0; i < 4; ++i)
    tile[ty + i * 8][tx] = src[(size_t)(y0 + ty + i * 8) * 1024 + x0 + tx];
  __syncthreads();
#pragma unroll
  for (int i = 0; i < 4; ++i)
    dst[(size_t)(x0 + ty + i * 8) * 1024 + y0 + tx] = to_bf16(tile[tx][ty + i * 8]);
}

// ---------------- fused QKV GEMM: 128x128 tile, z selects q/k/v ----------
// z=0: C=Qb (scaled by QSC); z=1: C=Kb; z=2: C=VTb in [b][h][d][s] layout.
__global__ __launch_bounds__(256) void gemm_qkv(const u16* __restrict__ X,
                                                const u16* __restrict__ WT,
                                                u16* __restrict__ Qb,
                                                u16* __restrict__ Kb,
                                                u16* __restrict__ VTb) {
  __shared__ u16 As[128 * 32];
  __shared__ u16 Bs[128 * 32];
  const int z = blockIdx.z;
  const u16* A = X + (size_t)z * 4194304;
  const u16* BT = WT + (size_t)z * 1048576;
  const int tid = threadIdx.x;
  const int w = tid >> 6, lane = tid & 63;
  const int g = lane >> 4, c = lane & 15;
  const int wr = w >> 1, wc = w & 1;
  const int row0 = blockIdx.x * 128;
  const int n0 = blockIdx.y * 128;

  f32x4 acc[4][4];
#pragma unroll
  for (int i = 0; i < 4; ++i)
#pragma unroll
    for (int j = 0; j < 4; ++j) acc[i][j] = (f32x4){0.f, 0.f, 0.f, 0.f};

  const int sub = lane >> 2;
  const int kk = (lane & 3) * 8;

  for (int kt = 0; kt < 32; ++kt) {
    const int k0 = kt * 32;
#pragma unroll
    for (int it = 0; it < 2; ++it) {
      const int ch = w * 2 + it;
      const int row = ch * 16 + sub;
      gload_lds16(A + (size_t)(row0 + row) * 1024 + k0 + kk, (char*)As + ch * 1024);
      gload_lds16(BT + (size_t)(n0 + row) * 1024 + k0 + kk, (char*)Bs + ch * 1024);
    }
    __syncthreads();

    bf16x8 af[4], bfr[4];
#pragma unroll
    for (int mi = 0; mi < 4; ++mi)
      af[mi] = frag_cast(*(const s16x8*)((const char*)As + (wr * 64 + mi * 16 + c) * 64 + g * 16));
#pragma unroll
    for (int ni = 0; ni < 4; ++ni)
      bfr[ni] = frag_cast(*(const s16x8*)((const char*)Bs + (wc * 64 + ni * 16 + c) * 64 + g * 16));
#pragma unroll
    for (int mi = 0; mi < 4; ++mi)
#pragma unroll
      for (int ni = 0; ni < 4; ++ni)
        acc[mi][ni] = mfma16(af[mi], bfr[ni], acc[mi][ni]);
    __syncthreads();
  }

  const float sc = (z == 0) ? QSC : 1.0f;
#pragma unroll
  for (int mi = 0; mi < 4; ++mi) {
    const int rowb = row0 + wr * 64 + mi * 16 + g * 4;
#pragma unroll
    for (int ni = 0; ni < 4; ++ni) {
      const int col = n0 + wc * 64 + ni * 16 + c;
#pragma unroll
      for (int r = 0; r < 4; ++r) {
        const int row = rowb + r;
        const float v = acc[mi][ni][r] * sc;
        if (z == 2) {
          const int b = row >> 11, s = row & 2047;
          const int hh = col >> 6, d = col & 63;
          VTb[((size_t)((b * 16 + hh) * 64 + d)) * 2048 + s] = to_bf16(v);
        } else {
          u16* C = z == 0 ? Qb : Kb;
          C[(size_t)row * 1024 + col] = to_bf16(v);
        }
      }
    }
  }
}

// ---------------- out projection GEMM: BM=64, BN=128, f32 out ------------
__global__ __launch_bounds__(256) void gemm_out(const u16* __restrict__ A,
                                                const u16* __restrict__ BT,
                                                float* __restrict__ C) {
  __shared__ u16 As[64 * 32];
  __shared__ u16 Bs[128 * 32];
  const int tid = threadIdx.x;
  const int w = tid >> 6, lane = tid & 63;
  const int g = lane >> 4, c = lane & 15;
  const int wr = w >> 1, wc = w & 1;   // wr: 32-row group, wc: 64-col group
  const int row0 = blockIdx.x * 64;
  const int n0 = blockIdx.y * 128;

  f32x4 acc[2][4];
#pragma unroll
  for (int i = 0; i < 2; ++i)
#pragma unroll
    for (int j = 0; j < 4; ++j) acc[i][j] = (f32x4){0.f, 0.f, 0.f, 0.f};

  const int sub = lane >> 2;
  const int kk = (lane & 3) * 8;

  for (int kt = 0; kt < 32; ++kt) {
    const int k0 = kt * 32;
    {  // A: 4 chunks of 16 rows; wave w stages chunk w
      const int row = w * 16 + sub;
      gload_lds16(A + (size_t)(row0 + row) * 1024 + k0 + kk, (char*)As + w * 1024);
    }
#pragma unroll
    for (int it = 0; it < 2; ++it) {  // B: 8 chunks; wave w stages 2w,2w+1
      const int ch = w * 2 + it;
      const int row = ch * 16 + sub;
      gload_lds16(BT + (size_t)(n0 + row) * 1024 + k0 + kk, (char*)Bs + ch * 1024);
    }
    __syncthreads();

    bf16x8 af[2], bfr[4];
#pragma unroll
    for (int mi = 0; mi < 2; ++mi)
      af[mi] = frag_cast(*(const s16x8*)((const char*)As + (wr * 32 + mi * 16 + c) * 64 + g * 16));
#pragma unroll
    for (int ni = 0; ni < 4; ++ni)
      bfr[ni] = frag_cast(*(const s16x8*)((const char*)Bs + (wc * 64 + ni * 16 + c) * 64 + g * 16));
#pragma unroll
    for (int mi = 0; mi < 2; ++mi)
#pragma unroll
      for (int ni = 0; ni < 4; ++ni)
        acc[mi][ni] = mfma16(af[mi], bfr[ni], acc[mi][ni]);
    __syncthreads();
  }

#pragma unroll
  for (int mi = 0; mi < 2; ++mi) {
    const int rowb = row0 + wr * 32 + mi * 16 + g * 4;
#pragma unroll
    for (int ni = 0; ni < 4; ++ni) {
      const int col = n0 + wc * 64 + ni * 16 + c;
#pragma unroll
      for (int r = 0; r < 4; ++r)
        C[(size_t)(rowb + r) * 1024 + col] = acc[mi][ni][r];
    }
  }
}

// ---------------- causal flash attention ----------------------------------
// grid (32, 32): x = q-tile (64 rows), y = b*16+h. 4 waves x 16 q-rows.
// Swapped QK^T (S^T = K*Q^T). Scores arrive pre-scaled in exp2 domain.
// Tiles t<qt: fully live (no mask code). Tile t==qt: diagonal (masked).
__global__ __launch_bounds__(256) void attn_fwd(const u16* __restrict__ Qb,
                                                const u16* __restrict__ Kb,
                                                const u16* __restrict__ VTb,
                                                u16* __restrict__ Ob) {
  __shared__ u16 Ks[64 * 64];     // [kv][d] swizzled
  __shared__ u16 VTs[64 * 64];    // [d][kv] swizzled
  __shared__ u16 Ps[4][16 * 64];  // per-wave [q][kv] swizzled

  const int tid = threadIdx.x;
  const int w = tid >> 6, lane = tid & 63;
  const int g = lane >> 4, c = lane & 15;
  const int qt = blockIdx.x;
  const int bh = blockIdx.y;
  const int b = bh >> 4, h = bh & 15;
  const int q0w = qt * 64 + w * 16;

  // Q fragments (B-operand: n=q, k=d) live in registers
  bf16x8 qfr[2];
#pragma unroll
  for (int ch = 0; ch < 2; ++ch)
    qfr[ch] = frag_cast(*(const s16x8*)(Qb + (size_t)(b * SEQ + q0w + c) * 1024 + h * 64 + ch * 32 + g * 8));

  f32x4 oacc[4];
#pragma unroll
  for (int j = 0; j < 4; ++j) oacc[j] = (f32x4){0.f, 0.f, 0.f, 0.f};
  float m_run = -1e30f;
  float l_run = 0.f;

  const int srow = tid >> 3;       // 0..31
  const int scol = (tid & 7) * 8;  // 0..56

  for (int t = 0; t <= qt; ++t) {
    const int kv0 = t * 64;
    // stage K [64][64] and V^T [64][64], XOR-swizzled rows
#pragma unroll
    for (int it = 0; it < 2; ++it) {
      const int r = srow + it * 32;
      const s16x8 kvv = *(const s16x8*)(Kb + (size_t)(b * SEQ + kv0 + r) * 1024 + h * 64 + scol);
      const s16x8 vvv = *(const s16x8*)(VTb + ((size_t)(bh * 64 + r)) * 2048 + kv0 + scol);
      const int sw = (scol * 2) ^ ((r & 7) << 4);
      *(s16x8*)((char*)Ks + r * 128 + sw) = kvv;
      *(s16x8*)((char*)VTs + r * 128 + sw) = vvv;
    }
    __syncthreads();

    // ---- S^T = K * Q^T : [kv 64][q 16]
    f32x4 sa[4];
#pragma unroll
    for (int i = 0; i < 4; ++i) sa[i] = (f32x4){0.f, 0.f, 0.f, 0.f};
#pragma unroll
    for (int kvf = 0; kvf < 4; ++kvf) {
      const int kr = kvf * 16 + c;
      const int rb = kr * 128, swz = (kr & 7) << 4;
#pragma unroll
      for (int ch = 0; ch < 2; ++ch) {
        const bf16x8 ak = frag_cast(*(const s16x8*)((char*)Ks + rb + ((ch * 64 + g * 16) ^ swz)));
        sa[kvf] = mfma16(ak, qfr[ch], sa[kvf]);
      }
    }

    // ---- online softmax in exp2 domain (per q-column = lane c)
    float pv[4][4];
    float mt = -1e30f;
    if (t == qt) {  // diagonal tile: apply causal mask
      const int q_abs = q0w + c;
#pragma unroll
      for (int kvf = 0; kvf < 4; ++kvf)
#pragma unroll
        for (int r = 0; r < 4; ++r) {
          const int kv_abs = kv0 + kvf * 16 + g * 4 + r;
          float s = sa[kvf][r];
          if (kv_abs > q_abs) s = -30000.f;
          pv[kvf][r] = s;
          mt = fmaxf(mt, s);
        }
    } else {        // fully live: no mask code at all
#pragma unroll
      for (int kvf = 0; kvf < 4; ++kvf)
#pragma unroll
        for (int r = 0; r < 4; ++r) {
          const float s = sa[kvf][r];
          pv[kvf][r] = s;
          mt = fmaxf(mt, s);
        }
    }
    mt = fmaxf(mt, __shfl_xor(mt, 16));
    mt = fmaxf(mt, __shfl_xor(mt, 32));

    // defer-max (T13): only rescale when some column grew by > 8 (exp2 dom)
    if (__any(mt > m_run + 8.f)) {
      const float m_new = fmaxf(m_run, mt);
      const float alpha = __builtin_amdgcn_exp2f(m_run - m_new);
      m_run = m_new;
#pragma unroll
      for (int r = 0; r < 4; ++r) {
        const float ar = __shfl(alpha, g * 4 + r);
#pragma unroll
        for (int df = 0; df < 4; ++df) oacc[df][r] *= ar;
      }
      l_run *= alpha;
    }

    float ls = 0.f;
    const int qrow = c;
    const int qswz = (qrow & 7) << 4;
#pragma unroll
    for (int kvf = 0; kvf < 4; ++kvf) {
      u16x4 pk;
#pragma unroll
      for (int r = 0; r < 4; ++r) {
        const float p = __builtin_amdgcn_exp2f(pv[kvf][r] - m_run);
        ls += p;
        pk[r] = to_bf16(p);
      }
      *(u16x4*)((char*)Ps[w] + qrow * 128 + (((kvf * 16 + g * 4) * 2) ^ qswz)) = pk;
    }
    ls += __shfl_xor(ls, 16);
    ls += __shfl_xor(ls, 32);
    l_run += ls;

    // ---- O += P * V
#pragma unroll
    for (int ch = 0; ch < 2; ++ch) {
      const bf16x8 ap = frag_cast(*(const s16x8*)((char*)Ps[w] + qrow * 128 +
                                                  ((ch * 64 + g * 16) ^ qswz)));
#pragma unroll
      for (int df = 0; df < 4; ++df) {
        const int dr = df * 16 + c;
        const bf16x8 bv = frag_cast(*(const s16x8*)((char*)VTs + dr * 128 +
                                                    ((ch * 64 + g * 16) ^ ((dr & 7) << 4))));
        oacc[df] = mfma16(ap, bv, oacc[df]);
      }
    }
    __syncthreads();
  }

  // epilogue: normalize by l_run, store bf16 [b][s][h*64+d]
  const float li = 1.f / l_run;
#pragma unroll
  for (int r = 0; r < 4; ++r) {
    const float lr = __shfl(li, g * 4 + r);
    const int q_abs = q0w + g * 4 + r;
#pragma unroll
    for (int df = 0; df < 4; ++df)
      Ob[(size_t)(b * SEQ + q_abs) * 1024 + h * 64 + df * 16 + c] = to_bf16(oacc[df][r] * lr);
  }
}

// --------------------------------------------------------------------------
extern "C" void kernel_launch(void* const* d_in, const int* in_sizes, int n_in,
                              void* d_out, int out_size, void* d_ws, size_t ws_size,
                              hipStream_t stream) {
  const float* query = (const float*)d_in[0];
  const float* key_ = (const float*)d_in[1];
  const float* value = (const float*)d_in[2];
  const float* w_q = (const float*)d_in[3];
  const float* w_k = (const float*)d_in[4];
  const float* w_v = (const float*)d_in[5];
  const float* w_o = (const float*)d_in[6];

  char* ws = (char*)d_ws;
  u16* xq = (u16*)(ws + 0);
  u16* wT = (u16*)(ws + 25165824);
  u16* Qb = (u16*)(ws + 33554432);
  u16* Kb = (u16*)(ws + 41943040);
  u16* VTb = (u16*)(ws + 50331648);
  u16* Ob = (u16*)(ws + 58720256);

  convert_x<<<dim3(512, 1, 3), 256, 0, stream>>>(query, key_, value, xq);
  transpose_w<<<dim3(32, 32, 4), dim3(32, 8), 0, stream>>>(w_q, w_k, w_v, w_o, wT);
  gemm_qkv<<<dim3(32, 8, 3), 256, 0, stream>>>(xq, wT, Qb, Kb, VTb);
  attn_fwd<<<dim3(32, 32), 256, 0, stream>>>(Qb, Kb, VTb, Ob);
  gemm_out<<<dim3(64, 8), 256, 0, stream>>>(Ob, wT + 3145728, (float*)d_out);
}